// Round 1
// baseline (1854.408 us; speedup 1.0000x reference)
//
#include <hip/hip_runtime.h>
#include <math.h>

typedef unsigned short u16;
typedef u16 u16x8 __attribute__((ext_vector_type(8)));
typedef __bf16 bf16x8 __attribute__((ext_vector_type(8)));
typedef float f32x4 __attribute__((ext_vector_type(4)));

#define HID 200
#define G4H 800
#define TLEN 128
#define LATENT 128
#define NCODES 1024
#define DIN 768
#define DCOND 1536
#define NB 256
#define MROWS (NB * TLEN)
#define LDG 896
#define LDH1 256
#define LDH2 512
#define NOUT 768
#define LSTR 40  // LDS row stride in bf16 elems (32 data + 8 pad)

__device__ __forceinline__ u16 f2b(float f) {
  union { float f; unsigned u; } v; v.f = f;
  unsigned r = v.u + 0x7fffu + ((v.u >> 16) & 1u);
  return (u16)(r >> 16);
}
__device__ __forceinline__ float b2f(u16 h) {
  union { unsigned u; float f; } v; v.u = ((unsigned)h) << 16;
  return v.f;
}
__device__ __forceinline__ float sigf(float x) { return 1.f / (1.f + __expf(-x)); }

// ---------------- weight convert + pad ----------------
__global__ void cvt_pad(const float* __restrict__ src, u16* __restrict__ dst,
                        int nr, int nc, int lds, int col0, int NRp, int KP) {
  int i = blockIdx.x * blockDim.x + threadIdx.x;
  if (i >= NRp * KP) return;
  int r = i / KP, c = i - r * KP;
  float v = (r < nr && c < nc) ? src[(size_t)r * lds + col0 + c] : 0.f;
  dst[i] = f2b(v);
}

__global__ void pad_f32(const float* __restrict__ src, float* __restrict__ dst,
                        int n, int npad) {
  int i = blockIdx.x * blockDim.x + threadIdx.x;
  if (i < npad) dst[i] = (i < n) ? src[i] : 0.f;
}

// ---------------- bf16 MFMA GEMM: C[M,N] = A[M,K] * B[N,K]^T (+epilogue) ----------------
enum { EPI_GATES = 0, EPI_H1 = 1, EPI_H2 = 2, EPI_OUT = 3 };

__device__ __forceinline__ f32x4 mfma16(bf16x8 a, bf16x8 b, f32x4 c) {
  return __builtin_amdgcn_mfma_f32_16x16x32_bf16(a, b, c, 0, 0, 0);
}

template<bool AF32, int EPI>
__global__ __launch_bounds__(256) void gemm_bf16(
    const void* __restrict__ Ap, const u16* __restrict__ Bp,
    void* __restrict__ Cp, int K, int ldc, const float* __restrict__ bias) {
  __shared__ __attribute__((aligned(16))) u16 As[128 * LSTR];
  __shared__ __attribute__((aligned(16))) u16 Bs[128 * LSTR];
  const int t = threadIdx.x;
  const int tileN = blockIdx.x * 128;
  const int tileM = blockIdx.y * 128;
  const int srow = t >> 1;
  const int shalf = (t & 1) * 16;
  const int l = t & 63;
  const int w = t >> 6;
  const int wr = (w >> 1) * 64;
  const int wc = (w & 1) * 64;
  const int fr = l & 15;
  const int fg = l >> 4;

  f32x4 acc[4][4];
#pragma unroll
  for (int m = 0; m < 4; ++m)
#pragma unroll
    for (int n = 0; n < 4; ++n) {
      f32x4 z = {0.f, 0.f, 0.f, 0.f};
      acc[m][n] = z;
    }

  for (int k0 = 0; k0 < K; k0 += 32) {
    // stage B tile (always bf16)
    {
      const u16* s = Bp + (size_t)(tileN + srow) * K + k0 + shalf;
      u16x8 v0 = *(const u16x8*)s;
      u16x8 v1 = *(const u16x8*)(s + 8);
      *(u16x8*)&Bs[srow * LSTR + shalf] = v0;
      *(u16x8*)&Bs[srow * LSTR + shalf + 8] = v1;
    }
    // stage A tile
    if constexpr (AF32) {
      const float* s = (const float*)Ap + (size_t)(tileM + srow) * K + k0 + shalf;
      float4 f0 = *(const float4*)(s);
      float4 f1 = *(const float4*)(s + 4);
      float4 f2 = *(const float4*)(s + 8);
      float4 f3 = *(const float4*)(s + 12);
      u16x8 o0, o1;
      o0[0] = f2b(f0.x); o0[1] = f2b(f0.y); o0[2] = f2b(f0.z); o0[3] = f2b(f0.w);
      o0[4] = f2b(f1.x); o0[5] = f2b(f1.y); o0[6] = f2b(f1.z); o0[7] = f2b(f1.w);
      o1[0] = f2b(f2.x); o1[1] = f2b(f2.y); o1[2] = f2b(f2.z); o1[3] = f2b(f2.w);
      o1[4] = f2b(f3.x); o1[5] = f2b(f3.y); o1[6] = f2b(f3.z); o1[7] = f2b(f3.w);
      *(u16x8*)&As[srow * LSTR + shalf] = o0;
      *(u16x8*)&As[srow * LSTR + shalf + 8] = o1;
    } else {
      const u16* s = (const u16*)Ap + (size_t)(tileM + srow) * K + k0 + shalf;
      u16x8 v0 = *(const u16x8*)s;
      u16x8 v1 = *(const u16x8*)(s + 8);
      *(u16x8*)&As[srow * LSTR + shalf] = v0;
      *(u16x8*)&As[srow * LSTR + shalf + 8] = v1;
    }
    __syncthreads();

    bf16x8 av[4], bv[4];
#pragma unroll
    for (int m = 0; m < 4; ++m)
      av[m] = __builtin_bit_cast(bf16x8, *(const u16x8*)&As[(wr + m * 16 + fr) * LSTR + fg * 8]);
#pragma unroll
    for (int n = 0; n < 4; ++n)
      bv[n] = __builtin_bit_cast(bf16x8, *(const u16x8*)&Bs[(wc + n * 16 + fr) * LSTR + fg * 8]);
#pragma unroll
    for (int m = 0; m < 4; ++m)
#pragma unroll
      for (int n = 0; n < 4; ++n)
        acc[m][n] = mfma16(av[m], bv[n], acc[m][n]);
    __syncthreads();
  }

  // epilogue: C layout per frag: row = (l>>4)*4 + reg, col = l&15
#pragma unroll
  for (int m = 0; m < 4; ++m) {
#pragma unroll
    for (int n = 0; n < 4; ++n) {
      const int gcol = tileN + wc + n * 16 + fr;
      const int growb = tileM + wr + m * 16 + fg * 4;
#pragma unroll
      for (int r = 0; r < 4; ++r) {
        const int grow = growb + r;
        float v = acc[m][n][r];
        if constexpr (EPI == EPI_GATES) {
          ((u16*)Cp)[(size_t)grow * ldc + gcol] = f2b(v);
        } else if constexpr (EPI == EPI_H1) {
          v += bias[(grow >> 7) * 256 + gcol];   // p1[b][col]
          v = fmaxf(v, 0.f);
          ((u16*)Cp)[(size_t)grow * ldc + gcol] = f2b(v);
        } else if constexpr (EPI == EPI_H2) {
          v += bias[gcol];
          v = fmaxf(v, 0.f);
          ((u16*)Cp)[(size_t)grow * ldc + gcol] = f2b(v);
        } else {
          v += bias[gcol];
          ((float*)Cp)[(size_t)grow * ldc + gcol] = sigf(v);
        }
      }
    }
  }
}

// ---------------- fused LSTM scan + encoder + VQ + p1 ----------------
// one block per batch element; thread r<800 owns W_hh row r in registers
__global__ __launch_bounds__(832) void lstm_enc(
    const u16* __restrict__ gates, const float* __restrict__ Whh,
    const float* __restrict__ b_ih, const float* __restrict__ b_hh,
    const float* __restrict__ Wenc, const float* __restrict__ b_enc,
    const float* __restrict__ emb, const float* __restrict__ W1,
    const float* __restrict__ b1, const float* __restrict__ noise,
    float* __restrict__ p1) {
  __shared__ __attribute__((aligned(16))) float sh_h[HID];
  __shared__ float sh_g[G4H];
  __shared__ __attribute__((aligned(16))) float sh_ze[LATENT];
  __shared__ float sh_zq[LATENT];
  __shared__ float sh_rd[832];
  __shared__ int sh_ri[832];
  const int r = threadIdx.x;
  const int b = blockIdx.x;

  float w[HID];
  float biasr = 0.f;
  if (r < G4H) {
#pragma unroll
    for (int q = 0; q < HID / 4; ++q) {
      float4 v = *(const float4*)&Whh[(size_t)r * HID + q * 4];
      w[q * 4 + 0] = v.x; w[q * 4 + 1] = v.y; w[q * 4 + 2] = v.z; w[q * 4 + 3] = v.w;
    }
    biasr = b_ih[r] + b_hh[r];
  }
  if (r < HID) sh_h[r] = 0.f;
  float c = 0.f;
  __syncthreads();

  for (int t = 0; t < TLEN; ++t) {
    float g = 0.f;
    if (r < G4H) {
      g = biasr + b2f(gates[(size_t)(b * TLEN + t) * LDG + r]);
#pragma unroll
      for (int q = 0; q < HID / 4; ++q) {
        float4 h4 = *(const float4*)&sh_h[q * 4];
        g = fmaf(w[q * 4 + 0], h4.x, g);
        g = fmaf(w[q * 4 + 1], h4.y, g);
        g = fmaf(w[q * 4 + 2], h4.z, g);
        g = fmaf(w[q * 4 + 3], h4.w, g);
      }
    }
    __syncthreads();           // all reads of sh_h done
    if (r < G4H) sh_g[r] = g;
    __syncthreads();           // gates visible
    if (r < HID) {
      float gi = sh_g[r], gf = sh_g[HID + r], gg = sh_g[2 * HID + r], go = sh_g[3 * HID + r];
      c = sigf(gf) * c + sigf(gi) * tanhf(gg);
      sh_h[r] = sigf(go) * tanhf(c);
    }
    __syncthreads();           // new h visible
  }

  // encoder: z_e = h @ Wenc^T + b_enc
  if (r < LATENT) {
    float z = b_enc[r];
#pragma unroll 4
    for (int k = 0; k < HID; ++k) z = fmaf(Wenc[(size_t)r * HID + k], sh_h[k], z);
    sh_ze[r] = z;
  }
  __syncthreads();

  // VQ: argmin_k ||e_k||^2 - 2 z_e . e_k
  float best = INFINITY; int bi = 0;
  for (int k = r; k < NCODES; k += 832) {
    float d = 0.f;
#pragma unroll
    for (int q = 0; q < LATENT / 4; ++q) {
      float4 e = *(const float4*)&emb[(size_t)k * LATENT + q * 4];
      float4 z = *(const float4*)&sh_ze[q * 4];
      d += e.x * (e.x - 2.f * z.x) + e.y * (e.y - 2.f * z.y)
         + e.z * (e.z - 2.f * z.z) + e.w * (e.w - 2.f * z.w);
    }
    if (d < best) { best = d; bi = k; }
  }
  sh_rd[r] = best; sh_ri[r] = bi;
  __syncthreads();
  for (int s = 512; s > 0; s >>= 1) {
    if (r < s && r + s < 832) {
      float od = sh_rd[r + s]; int oi = sh_ri[r + s];
      if (od < sh_rd[r] || (od == sh_rd[r] && oi < sh_ri[r])) { sh_rd[r] = od; sh_ri[r] = oi; }
    }
    __syncthreads();
  }
  const int kmin = sh_ri[0];
  if (r < LATENT) sh_zq[r] = emb[(size_t)kmin * LATENT + r];
  __syncthreads();

  // p1[b][j] = b1 + W1[:,0:128].zq + W1[:,1664:2432].noise   (pad cols 200..255 = 0)
  if (r < 256) {
    float v = 0.f;
    if (r < HID) {
      v = b1[r];
      const float* wrow = W1 + (size_t)r * 2432;
#pragma unroll 4
      for (int d = 0; d < LATENT; ++d) v = fmaf(wrow[d], sh_zq[d], v);
      const float* nz = noise + (size_t)b * DIN;
#pragma unroll 4
      for (int d = 0; d < DIN; ++d) v = fmaf(wrow[1664 + d], nz[d], v);
    }
    p1[b * 256 + r] = v;
  }
}

// ---------------- host ----------------
extern "C" void kernel_launch(void* const* d_in, const int* in_sizes, int n_in,
                              void* d_out, int out_size, void* d_ws, size_t ws_size,
                              hipStream_t stream) {
  const float* x     = (const float*)d_in[0];
  const float* cond  = (const float*)d_in[1];
  const float* noise = (const float*)d_in[2];
  const float* W_ih  = (const float*)d_in[3];
  const float* W_hh  = (const float*)d_in[4];
  const float* b_ih  = (const float*)d_in[5];
  const float* b_hh  = (const float*)d_in[6];
  const float* W_enc = (const float*)d_in[7];
  const float* b_enc = (const float*)d_in[8];
  const float* emb   = (const float*)d_in[9];
  const float* W1    = (const float*)d_in[10];
  const float* b1    = (const float*)d_in[11];
  const float* W2    = (const float*)d_in[12];
  const float* b2    = (const float*)d_in[13];
  const float* W3    = (const float*)d_in[14];
  const float* b3    = (const float*)d_in[15];

  char* ws = (char*)d_ws;
  size_t off = 0;
  auto alloc = [&](size_t bytes) -> void* {
    void* p = ws + off; off += (bytes + 255) & ~(size_t)255; return p;
  };
  u16*   W_ihb = (u16*)alloc((size_t)896 * 768 * 2);
  u16*   W1cb  = (u16*)alloc((size_t)256 * 1536 * 2);
  u16*   W2b   = (u16*)alloc((size_t)512 * 256 * 2);
  u16*   W3b   = (u16*)alloc((size_t)768 * 512 * 2);
  float* b2p   = (float*)alloc(512 * 4);
  u16*   gates = (u16*)alloc((size_t)MROWS * LDG * 2);
  float* p1    = (float*)alloc(256 * 256 * 4);
  u16*   h1    = (u16*)alloc((size_t)MROWS * LDH1 * 2);
  u16*   h2    = (u16*)alloc((size_t)MROWS * LDH2 * 2);

  // weight conversion / padding
  cvt_pad<<<dim3((896 * 768 + 255) / 256), 256, 0, stream>>>(W_ih, W_ihb, 800, 768, 768, 0, 896, 768);
  cvt_pad<<<dim3((256 * 1536 + 255) / 256), 256, 0, stream>>>(W1, W1cb, 200, 1536, 2432, 128, 256, 1536);
  cvt_pad<<<dim3((512 * 256 + 255) / 256), 256, 0, stream>>>(W2, W2b, 400, 200, 200, 0, 512, 256);
  cvt_pad<<<dim3((768 * 512 + 255) / 256), 256, 0, stream>>>(W3, W3b, 768, 400, 400, 0, 768, 512);
  pad_f32<<<dim3(2), 256, 0, stream>>>(b2, b2p, 400, 512);

  // gates = x @ W_ih^T  (bias added in lstm kernel), bf16 out, ld 896
  gemm_bf16<true, EPI_GATES><<<dim3(LDG / 128, MROWS / 128), 256, 0, stream>>>(
      x, W_ihb, gates, 768, LDG, nullptr);

  // LSTM scan + encoder + VQ + p1
  lstm_enc<<<dim3(NB), 832, 0, stream>>>(gates, W_hh, b_ih, b_hh, W_enc, b_enc,
                                         emb, W1, b1, noise, p1);

  // h1 = relu(cond @ W1c^T + p1[b])
  gemm_bf16<true, EPI_H1><<<dim3(LDH1 / 128, MROWS / 128), 256, 0, stream>>>(
      cond, W1cb, h1, DCOND, LDH1, p1);
  // h2 = relu(h1 @ W2^T + b2)
  gemm_bf16<false, EPI_H2><<<dim3(LDH2 / 128, MROWS / 128), 256, 0, stream>>>(
      h1, W2b, h2, LDH1, LDH2, b2p);
  // out = sigmoid(h2 @ W3^T + b3)
  gemm_bf16<false, EPI_OUT><<<dim3(NOUT / 128, MROWS / 128), 256, 0, stream>>>(
      h2, W3b, (float*)d_out, LDH2, NOUT, b3);
}

// Round 2
// 612.107 us; speedup vs baseline: 3.0295x; 3.0295x over previous
//
#include <hip/hip_runtime.h>
#include <hip/hip_fp16.h>
#include <math.h>

typedef unsigned short u16;
typedef u16 u16x8 __attribute__((ext_vector_type(8)));
typedef __bf16 bf16x8 __attribute__((ext_vector_type(8)));
typedef float f32x4 __attribute__((ext_vector_type(4)));

#define HID 200
#define G4H 800
#define TLEN 128
#define LATENT 128
#define NCODES 1024
#define DIN 768
#define DCOND 1536
#define NB 256
#define MROWS (NB * TLEN)
#define LDG 896
#define LDH1 256
#define LDH2 512
#define NOUT 768
#define LSTR 40  // LDS row stride in bf16 elems (32 data + 8 pad)

__device__ __forceinline__ u16 f2b(float f) {
  union { float f; unsigned u; } v; v.f = f;
  unsigned r = v.u + 0x7fffu + ((v.u >> 16) & 1u);
  return (u16)(r >> 16);
}
__device__ __forceinline__ float b2f(u16 h) {
  union { unsigned u; float f; } v; v.u = ((unsigned)h) << 16;
  return v.f;
}
__device__ __forceinline__ float sigf(float x) { return 1.f / (1.f + __expf(-x)); }
__device__ __forceinline__ float tanh_fast(float x) {
  return 1.f - 2.f / (__expf(2.f * x) + 1.f);
}

// ---------------- weight convert + pad ----------------
__global__ void cvt_pad(const float* __restrict__ src, u16* __restrict__ dst,
                        int nr, int nc, int lds, int col0, int NRp, int KP) {
  int i = blockIdx.x * blockDim.x + threadIdx.x;
  if (i >= NRp * KP) return;
  int r = i / KP, c = i - r * KP;
  float v = (r < nr && c < nc) ? src[(size_t)r * lds + col0 + c] : 0.f;
  dst[i] = f2b(v);
}

__global__ void pad_f32(const float* __restrict__ src, float* __restrict__ dst,
                        int n, int npad) {
  int i = blockIdx.x * blockDim.x + threadIdx.x;
  if (i < npad) dst[i] = (i < n) ? src[i] : 0.f;
}

// pack W_hh [800][200] fp32 -> Wt[q][r] __half2 (cols 2q,2q+1), coalesced layout;
// also combined bias
__global__ void pack_whh(const float* __restrict__ Whh, __half2* __restrict__ Wt,
                         const float* __restrict__ b_ih, const float* __restrict__ b_hh,
                         float* __restrict__ biasc) {
  int i = blockIdx.x * blockDim.x + threadIdx.x;
  if (i < 100 * 800) {
    int q = i / 800, r = i - q * 800;
    float a = Whh[(size_t)r * HID + 2 * q];
    float b = Whh[(size_t)r * HID + 2 * q + 1];
    Wt[(size_t)q * 800 + r] = __floats2half2_rn(a, b);
  }
  if (i < G4H) biasc[i] = b_ih[i] + b_hh[i];
}

// ---------------- bf16 MFMA GEMM: C[M,N] = A[M,K] * B[N,K]^T (+epilogue) ----------------
enum { EPI_GATES = 0, EPI_H1 = 1, EPI_H2 = 2, EPI_OUT = 3 };

__device__ __forceinline__ f32x4 mfma16(bf16x8 a, bf16x8 b, f32x4 c) {
  return __builtin_amdgcn_mfma_f32_16x16x32_bf16(a, b, c, 0, 0, 0);
}

template<bool AF32, int EPI>
__global__ __launch_bounds__(256) void gemm_bf16(
    const void* __restrict__ Ap, const u16* __restrict__ Bp,
    void* __restrict__ Cp, int K, int ldc, const float* __restrict__ bias) {
  __shared__ __attribute__((aligned(16))) u16 As[128 * LSTR];
  __shared__ __attribute__((aligned(16))) u16 Bs[128 * LSTR];
  const int t = threadIdx.x;
  const int tileN = blockIdx.x * 128;
  const int tileM = blockIdx.y * 128;
  const int srow = t >> 1;
  const int shalf = (t & 1) * 16;
  const int l = t & 63;
  const int w = t >> 6;
  const int wr = (w >> 1) * 64;
  const int wc = (w & 1) * 64;
  const int fr = l & 15;
  const int fg = l >> 4;

  f32x4 acc[4][4];
#pragma unroll
  for (int m = 0; m < 4; ++m)
#pragma unroll
    for (int n = 0; n < 4; ++n) {
      f32x4 z = {0.f, 0.f, 0.f, 0.f};
      acc[m][n] = z;
    }

  for (int k0 = 0; k0 < K; k0 += 32) {
    // stage B tile (always bf16)
    {
      const u16* s = Bp + (size_t)(tileN + srow) * K + k0 + shalf;
      u16x8 v0 = *(const u16x8*)s;
      u16x8 v1 = *(const u16x8*)(s + 8);
      *(u16x8*)&Bs[srow * LSTR + shalf] = v0;
      *(u16x8*)&Bs[srow * LSTR + shalf + 8] = v1;
    }
    // stage A tile
    if constexpr (AF32) {
      const float* s = (const float*)Ap + (size_t)(tileM + srow) * K + k0 + shalf;
      float4 f0 = *(const float4*)(s);
      float4 f1 = *(const float4*)(s + 4);
      float4 f2 = *(const float4*)(s + 8);
      float4 f3 = *(const float4*)(s + 12);
      u16x8 o0, o1;
      o0[0] = f2b(f0.x); o0[1] = f2b(f0.y); o0[2] = f2b(f0.z); o0[3] = f2b(f0.w);
      o0[4] = f2b(f1.x); o0[5] = f2b(f1.y); o0[6] = f2b(f1.z); o0[7] = f2b(f1.w);
      o1[0] = f2b(f2.x); o1[1] = f2b(f2.y); o1[2] = f2b(f2.z); o1[3] = f2b(f2.w);
      o1[4] = f2b(f3.x); o1[5] = f2b(f3.y); o1[6] = f2b(f3.z); o1[7] = f2b(f3.w);
      *(u16x8*)&As[srow * LSTR + shalf] = o0;
      *(u16x8*)&As[srow * LSTR + shalf + 8] = o1;
    } else {
      const u16* s = (const u16*)Ap + (size_t)(tileM + srow) * K + k0 + shalf;
      u16x8 v0 = *(const u16x8*)s;
      u16x8 v1 = *(const u16x8*)(s + 8);
      *(u16x8*)&As[srow * LSTR + shalf] = v0;
      *(u16x8*)&As[srow * LSTR + shalf + 8] = v1;
    }
    __syncthreads();

    bf16x8 av[4], bv[4];
#pragma unroll
    for (int m = 0; m < 4; ++m)
      av[m] = __builtin_bit_cast(bf16x8, *(const u16x8*)&As[(wr + m * 16 + fr) * LSTR + fg * 8]);
#pragma unroll
    for (int n = 0; n < 4; ++n)
      bv[n] = __builtin_bit_cast(bf16x8, *(const u16x8*)&Bs[(wc + n * 16 + fr) * LSTR + fg * 8]);
#pragma unroll
    for (int m = 0; m < 4; ++m)
#pragma unroll
      for (int n = 0; n < 4; ++n)
        acc[m][n] = mfma16(av[m], bv[n], acc[m][n]);
    __syncthreads();
  }

  // epilogue: C layout per frag: row = (l>>4)*4 + reg, col = l&15
#pragma unroll
  for (int m = 0; m < 4; ++m) {
#pragma unroll
    for (int n = 0; n < 4; ++n) {
      const int gcol = tileN + wc + n * 16 + fr;
      const int growb = tileM + wr + m * 16 + fg * 4;
#pragma unroll
      for (int r = 0; r < 4; ++r) {
        const int grow = growb + r;
        float v = acc[m][n][r];
        if constexpr (EPI == EPI_GATES) {
          ((u16*)Cp)[(size_t)grow * ldc + gcol] = f2b(v);
        } else if constexpr (EPI == EPI_H1) {
          v += bias[(grow >> 7) * 256 + gcol];   // p1[b][col]
          v = fmaxf(v, 0.f);
          ((u16*)Cp)[(size_t)grow * ldc + gcol] = f2b(v);
        } else if constexpr (EPI == EPI_H2) {
          v += bias[gcol];
          v = fmaxf(v, 0.f);
          ((u16*)Cp)[(size_t)grow * ldc + gcol] = f2b(v);
        } else {
          v += bias[gcol];
          ((float*)Cp)[(size_t)grow * ldc + gcol] = sigf(v);
        }
      }
    }
  }
}

// ---------------- fused LSTM scan + encoder + VQ + p1 ----------------
// one block per batch element; thread r<800 owns W_hh row r as 100 half2 in regs
__global__ __launch_bounds__(832, 1) void lstm_enc(
    const u16* __restrict__ gates, const __half2* __restrict__ Wt,
    const float* __restrict__ biasc,
    const float* __restrict__ Wenc, const float* __restrict__ b_enc,
    const float* __restrict__ emb, const float* __restrict__ W1,
    const float* __restrict__ b1, const float* __restrict__ noise,
    float* __restrict__ p1) {
  __shared__ __attribute__((aligned(16))) __half2 sh_h2[100];  // h as fp16 pairs
  __shared__ __attribute__((aligned(16))) float sh_hf[HID];    // h fp32 (for encoder)
  __shared__ float sh_g[G4H];
  __shared__ __attribute__((aligned(16))) float sh_ze[LATENT];
  __shared__ float sh_zq[LATENT];
  __shared__ float sh_rd[832];
  __shared__ int sh_ri[832];
  const int r = threadIdx.x;
  const int b = blockIdx.x;
  const bool active = (r < G4H);
  const bool hthr = (r < 100);

  // weights: coalesced load (Wt[q*800 + r])
  __half2 wv[100];
  float biasr = 0.f;
  if (active) {
#pragma unroll
    for (int q = 0; q < 100; ++q) wv[q] = Wt[(size_t)q * 800 + r];
    biasr = biasc[r];
  }
  if (hthr) {
    sh_h2[r] = __floats2half2_rn(0.f, 0.f);
  }
  float c0 = 0.f, c1 = 0.f;
  float gv = active ? b2f(gates[(size_t)(b * TLEN) * LDG + r]) : 0.f;
  __syncthreads();

  for (int t = 0; t < TLEN; ++t) {
    // prefetch next step's gate value (hidden under dot + barriers)
    float gv_n = 0.f;
    if (active && t + 1 < TLEN)
      gv_n = b2f(gates[(size_t)(b * TLEN + t + 1) * LDG + r]);

    float g = 0.f;
    if (active) {
      __half2 a0 = __floats2half2_rn(0.f, 0.f), a1 = a0, a2 = a0, a3 = a0;
      const uint4* H = (const uint4*)sh_h2;
#pragma unroll
      for (int q4 = 0; q4 < 25; ++q4) {
        uint4 hv = H[q4];
        a0 = __hfma2(wv[4 * q4 + 0], __builtin_bit_cast(__half2, hv.x), a0);
        a1 = __hfma2(wv[4 * q4 + 1], __builtin_bit_cast(__half2, hv.y), a1);
        a2 = __hfma2(wv[4 * q4 + 2], __builtin_bit_cast(__half2, hv.z), a2);
        a3 = __hfma2(wv[4 * q4 + 3], __builtin_bit_cast(__half2, hv.w), a3);
      }
      a0 = __hadd2(__hadd2(a0, a1), __hadd2(a2, a3));
      g = biasr + gv + __low2float(a0) + __high2float(a0);
      sh_g[r] = g;
    }
    __syncthreads();           // gates visible; all sh_h2 reads done
    if (hthr) {
      const int i0 = 2 * r, i1 = 2 * r + 1;
      float gi0 = sh_g[i0], gf0 = sh_g[HID + i0], gg0 = sh_g[2 * HID + i0], go0 = sh_g[3 * HID + i0];
      float gi1 = sh_g[i1], gf1 = sh_g[HID + i1], gg1 = sh_g[2 * HID + i1], go1 = sh_g[3 * HID + i1];
      c0 = sigf(gf0) * c0 + sigf(gi0) * tanh_fast(gg0);
      c1 = sigf(gf1) * c1 + sigf(gi1) * tanh_fast(gg1);
      float h0 = sigf(go0) * tanh_fast(c0);
      float h1 = sigf(go1) * tanh_fast(c1);
      sh_h2[r] = __floats2half2_rn(h0, h1);
      sh_hf[i0] = h0; sh_hf[i1] = h1;
    }
    __syncthreads();           // new h visible
    gv = gv_n;
  }

  // encoder: z_e = h @ Wenc^T + b_enc
  if (r < LATENT) {
    float z = b_enc[r];
#pragma unroll 4
    for (int k = 0; k < HID; ++k) z = fmaf(Wenc[(size_t)r * HID + k], sh_hf[k], z);
    sh_ze[r] = z;
  }
  __syncthreads();

  // VQ: argmin_k ||e_k||^2 - 2 z_e . e_k
  float best = INFINITY; int bi = 0;
  for (int k = r; k < NCODES; k += 832) {
    float d = 0.f;
#pragma unroll
    for (int q = 0; q < LATENT / 4; ++q) {
      float4 e = *(const float4*)&emb[(size_t)k * LATENT + q * 4];
      float4 z = *(const float4*)&sh_ze[q * 4];
      d += e.x * (e.x - 2.f * z.x) + e.y * (e.y - 2.f * z.y)
         + e.z * (e.z - 2.f * z.z) + e.w * (e.w - 2.f * z.w);
    }
    if (d < best) { best = d; bi = k; }
  }
  sh_rd[r] = best; sh_ri[r] = bi;
  __syncthreads();
  for (int s = 512; s > 0; s >>= 1) {
    if (r < s && r + s < 832) {
      float od = sh_rd[r + s]; int oi = sh_ri[r + s];
      if (od < sh_rd[r] || (od == sh_rd[r] && oi < sh_ri[r])) { sh_rd[r] = od; sh_ri[r] = oi; }
    }
    __syncthreads();
  }
  const int kmin = sh_ri[0];
  if (r < LATENT) sh_zq[r] = emb[(size_t)kmin * LATENT + r];
  __syncthreads();

  // p1[b][j] = b1 + W1[:,0:128].zq + W1[:,1664:2432].noise   (pad cols 200..255 = 0)
  if (r < 256) {
    float v = 0.f;
    if (r < HID) {
      v = b1[r];
      const float* wrow = W1 + (size_t)r * 2432;
#pragma unroll 4
      for (int d = 0; d < LATENT; ++d) v = fmaf(wrow[d], sh_zq[d], v);
      const float* nz = noise + (size_t)b * DIN;
#pragma unroll 4
      for (int d = 0; d < DIN; ++d) v = fmaf(wrow[1664 + d], nz[d], v);
    }
    p1[b * 256 + r] = v;
  }
}

// ---------------- host ----------------
extern "C" void kernel_launch(void* const* d_in, const int* in_sizes, int n_in,
                              void* d_out, int out_size, void* d_ws, size_t ws_size,
                              hipStream_t stream) {
  const float* x     = (const float*)d_in[0];
  const float* cond  = (const float*)d_in[1];
  const float* noise = (const float*)d_in[2];
  const float* W_ih  = (const float*)d_in[3];
  const float* W_hh  = (const float*)d_in[4];
  const float* b_ih  = (const float*)d_in[5];
  const float* b_hh  = (const float*)d_in[6];
  const float* W_enc = (const float*)d_in[7];
  const float* b_enc = (const float*)d_in[8];
  const float* emb   = (const float*)d_in[9];
  const float* W1    = (const float*)d_in[10];
  const float* b1    = (const float*)d_in[11];
  const float* W2    = (const float*)d_in[12];
  const float* b2    = (const float*)d_in[13];
  const float* W3    = (const float*)d_in[14];
  const float* b3    = (const float*)d_in[15];

  char* ws = (char*)d_ws;
  size_t off = 0;
  auto alloc = [&](size_t bytes) -> void* {
    void* p = ws + off; off += (bytes + 255) & ~(size_t)255; return p;
  };
  u16*     W_ihb = (u16*)alloc((size_t)896 * 768 * 2);
  u16*     W1cb  = (u16*)alloc((size_t)256 * 1536 * 2);
  u16*     W2b   = (u16*)alloc((size_t)512 * 256 * 2);
  u16*     W3b   = (u16*)alloc((size_t)768 * 512 * 2);
  float*   b2p   = (float*)alloc(512 * 4);
  __half2* Wt    = (__half2*)alloc((size_t)100 * 800 * 4);
  float*   biasc = (float*)alloc(G4H * 4);
  u16*     gates = (u16*)alloc((size_t)MROWS * LDG * 2);
  float*   p1    = (float*)alloc(256 * 256 * 4);
  u16*     h1    = (u16*)alloc((size_t)MROWS * LDH1 * 2);
  u16*     h2    = (u16*)alloc((size_t)MROWS * LDH2 * 2);

  // weight conversion / padding
  cvt_pad<<<dim3((896 * 768 + 255) / 256), 256, 0, stream>>>(W_ih, W_ihb, 800, 768, 768, 0, 896, 768);
  cvt_pad<<<dim3((256 * 1536 + 255) / 256), 256, 0, stream>>>(W1, W1cb, 200, 1536, 2432, 128, 256, 1536);
  cvt_pad<<<dim3((512 * 256 + 255) / 256), 256, 0, stream>>>(W2, W2b, 400, 200, 200, 0, 512, 256);
  cvt_pad<<<dim3((768 * 512 + 255) / 256), 256, 0, stream>>>(W3, W3b, 768, 400, 400, 0, 768, 512);
  pad_f32<<<dim3(2), 256, 0, stream>>>(b2, b2p, 400, 512);
  pack_whh<<<dim3((100 * 800 + 255) / 256), 256, 0, stream>>>(W_hh, Wt, b_ih, b_hh, biasc);

  // gates = x @ W_ih^T  (bias added in lstm kernel), bf16 out, ld 896
  gemm_bf16<true, EPI_GATES><<<dim3(LDG / 128, MROWS / 128), 256, 0, stream>>>(
      x, W_ihb, gates, 768, LDG, nullptr);

  // LSTM scan + encoder + VQ + p1
  lstm_enc<<<dim3(NB), 832, 0, stream>>>(gates, Wt, biasc, W_enc, b_enc,
                                         emb, W1, b1, noise, p1);

  // h1 = relu(cond @ W1c^T + p1[b])
  gemm_bf16<true, EPI_H1><<<dim3(LDH1 / 128, MROWS / 128), 256, 0, stream>>>(
      cond, W1cb, h1, DCOND, LDH1, p1);
  // h2 = relu(h1 @ W2^T + b2)
  gemm_bf16<false, EPI_H2><<<dim3(LDH2 / 128, MROWS / 128), 256, 0, stream>>>(
      h1, W2b, h2, LDH1, LDH2, b2p);
  // out = sigmoid(h2 @ W3^T + b3)
  gemm_bf16<false, EPI_OUT><<<dim3(NOUT / 128, MROWS / 128), 256, 0, stream>>>(
      h2, W3b, (float*)d_out, LDH2, NOUT, b3);
}

// Round 3
// 577.380 us; speedup vs baseline: 3.2118x; 1.0601x over previous
//
#include <hip/hip_runtime.h>
#include <hip/hip_fp16.h>
#include <math.h>

typedef unsigned short u16;
typedef u16 u16x8 __attribute__((ext_vector_type(8)));
typedef __bf16 bf16x8 __attribute__((ext_vector_type(8)));
typedef float f32x4 __attribute__((ext_vector_type(4)));

#define HID 200
#define G4H 800
#define TLEN 128
#define LATENT 128
#define NCODES 1024
#define DIN 768
#define DCOND 1536
#define NB 256
#define MROWS (NB * TLEN)
#define LDG 896
#define LDH1 256
#define LDH2 512
#define NOUT 768

__device__ __forceinline__ u16 f2b(float f) {
  union { float f; unsigned u; } v; v.f = f;
  unsigned r = v.u + 0x7fffu + ((v.u >> 16) & 1u);
  return (u16)(r >> 16);
}
__device__ __forceinline__ float b2f(u16 h) {
  union { unsigned u; float f; } v; v.u = ((unsigned)h) << 16;
  return v.f;
}
__device__ __forceinline__ float sigf(float x) { return 1.f / (1.f + __expf(-x)); }
__device__ __forceinline__ float tanh_fast(float x) {
  return 1.f - 2.f / (__expf(2.f * x) + 1.f);
}

// async global->LDS, 16B per lane; LDS dest is wave-uniform base + lane*16
__device__ __forceinline__ void gl16(const void* g, void* l) {
  __builtin_amdgcn_global_load_lds(
      (const __attribute__((address_space(1))) void*)g,
      (__attribute__((address_space(3))) void*)l, 16, 0, 0);
}

// pack 2 f32 -> u32 of 2 bf16 (lo = first arg)
__device__ __forceinline__ unsigned cvtpk(float a, float b) {
  unsigned r;
  asm("v_cvt_pk_bf16_f32 %0, %1, %2" : "=v"(r) : "v"(a), "v"(b));
  return r;
}

// ---------------- weight convert + pad ----------------
__global__ void cvt_pad(const float* __restrict__ src, u16* __restrict__ dst,
                        int nr, int nc, int lds, int col0, int NRp, int KP) {
  int i = blockIdx.x * blockDim.x + threadIdx.x;
  if (i >= NRp * KP) return;
  int r = i / KP, c = i - r * KP;
  float v = (r < nr && c < nc) ? src[(size_t)r * lds + col0 + c] : 0.f;
  dst[i] = f2b(v);
}

__global__ void pad_f32(const float* __restrict__ src, float* __restrict__ dst,
                        int n, int npad) {
  int i = blockIdx.x * blockDim.x + threadIdx.x;
  if (i < npad) dst[i] = (i < n) ? src[i] : 0.f;
}

// W_hh [800][200] f32 -> Wt2[k][r] = half2(W[r][k], W[r+400][k]), k=0..199, r=0..399
__global__ void pack_whh(const float* __restrict__ Whh, __half2* __restrict__ Wt2,
                         const float* __restrict__ b_ih, const float* __restrict__ b_hh,
                         float* __restrict__ biasc) {
  int i = blockIdx.x * blockDim.x + threadIdx.x;
  if (i < 200 * 400) {
    int k = i / 400, r = i - k * 400;
    Wt2[i] = __floats2half2_rn(Whh[(size_t)r * HID + k], Whh[(size_t)(r + 400) * HID + k]);
  }
  if (i < G4H) biasc[i] = b_ih[i] + b_hh[i];
}

// ---------------- bf16 MFMA GEMM: C[M,N] = A[M,K] * B[N,K]^T (+epilogue) ----------------
// A,B staged via global_load_lds into LINEAR LDS with source-side XOR swizzle;
// reads apply the same XOR (involution). f32 A converted to bf16 at frag-read.
enum { EPI_GATES = 0, EPI_H1 = 1, EPI_H2 = 2, EPI_OUT = 3 };

__device__ __forceinline__ f32x4 mfma16(bf16x8 a, bf16x8 b, f32x4 c) {
  return __builtin_amdgcn_mfma_f32_16x16x32_bf16(a, b, c, 0, 0, 0);
}

template<bool AF32, int EPI>
__global__ __launch_bounds__(256) void gemm_bf16(
    const void* __restrict__ Ap, const u16* __restrict__ Bp,
    void* __restrict__ Cp, int K, int ldc, const float* __restrict__ bias) {
  // A tile: f32 [128][32] = 16KB  or bf16 [128][32] = 8KB ; B tile bf16 8KB
  __shared__ __attribute__((aligned(16))) char AsRaw[AF32 ? 128 * 32 * 4 : 128 * 32 * 2];
  __shared__ __attribute__((aligned(16))) u16 Bs[128 * 32];
  float* Asf = (float*)AsRaw;
  u16* As16 = (u16*)AsRaw;

  const int t = threadIdx.x;
  const int tileN = blockIdx.x * 128;
  const int tileM = blockIdx.y * 128;
  const int l = t & 63;
  const int w = t >> 6;
  const int wr = (w >> 1) * 64;
  const int wc = (w & 1) * 64;
  const int fr = l & 15;
  const int fg = l >> 4;

  // ---- staging source pointers (per-lane, pre-swizzled) ----
  // B: tile bytes tb = w*1024 + j*4096 + lane*16 ; row=tb>>6 ; granule gd=(tb>>4)&3
  //    src granule = gd ^ ((row>>1)&3)
  const u16* bsrc[2];
  u16* bdst[2];
#pragma unroll
  for (int j = 0; j < 2; ++j) {
    int tb = w * 1024 + j * 4096 + (t & 63) * 16;
    int row = tb >> 6, gd = (tb >> 4) & 3;
    bsrc[j] = Bp + (size_t)(tileN + row) * K + ((gd ^ ((row >> 1) & 3)) << 3);
    bdst[j] = Bs + w * 512 + j * 2048;  // wave-uniform
  }
  const float* asrcF[4];
  float* adstF[4];
  const u16* asrcH[2];
  u16* adstH[2];
  if constexpr (AF32) {
#pragma unroll
    for (int j = 0; j < 4; ++j) {
      int tb = w * 1024 + j * 4096 + (t & 63) * 16;
      int row = tb >> 7, gd = (tb >> 4) & 7;
      asrcF[j] = (const float*)Ap + (size_t)(tileM + row) * K + ((gd ^ (row & 7)) << 2);
      adstF[j] = Asf + w * 256 + j * 1024;
    }
  } else {
#pragma unroll
    for (int j = 0; j < 2; ++j) {
      int tb = w * 1024 + j * 4096 + (t & 63) * 16;
      int row = tb >> 6, gd = (tb >> 4) & 3;
      asrcH[j] = (const u16*)Ap + (size_t)(tileM + row) * K + ((gd ^ ((row >> 1) & 3)) << 3);
      adstH[j] = As16 + w * 512 + j * 2048;
    }
  }

  f32x4 acc[4][4];
#pragma unroll
  for (int m = 0; m < 4; ++m)
#pragma unroll
    for (int n = 0; n < 4; ++n) {
      f32x4 z = {0.f, 0.f, 0.f, 0.f};
      acc[m][n] = z;
    }

  for (int k0 = 0; k0 < K; k0 += 32) {
    // issue async stages for this k-tile
#pragma unroll
    for (int j = 0; j < 2; ++j) { gl16(bsrc[j], bdst[j]); bsrc[j] += 32; }
    if constexpr (AF32) {
#pragma unroll
      for (int j = 0; j < 4; ++j) { gl16(asrcF[j], adstF[j]); asrcF[j] += 32; }
    } else {
#pragma unroll
      for (int j = 0; j < 2; ++j) { gl16(asrcH[j], adstH[j]); asrcH[j] += 32; }
    }
    __syncthreads();  // vmcnt(0)+barrier: tiles resident

    bf16x8 av[4], bv[4];
#pragma unroll
    for (int m = 0; m < 4; ++m) {
      const int row = wr + m * 16 + fr;
      if constexpr (AF32) {
        const int g0 = (2 * fg) ^ (row & 7);
        const int g1 = (2 * fg + 1) ^ (row & 7);
        float4 p0 = *(const float4*)(Asf + row * 32 + g0 * 4);
        float4 p1 = *(const float4*)(Asf + row * 32 + g1 * 4);
        uint4 u;
        u.x = cvtpk(p0.x, p0.y); u.y = cvtpk(p0.z, p0.w);
        u.z = cvtpk(p1.x, p1.y); u.w = cvtpk(p1.z, p1.w);
        av[m] = __builtin_bit_cast(bf16x8, u);
      } else {
        const int g = fg ^ ((row >> 1) & 3);
        av[m] = __builtin_bit_cast(bf16x8, *(const u16x8*)(As16 + row * 32 + g * 8));
      }
    }
#pragma unroll
    for (int n = 0; n < 4; ++n) {
      const int row = wc + n * 16 + fr;
      const int g = fg ^ ((row >> 1) & 3);
      bv[n] = __builtin_bit_cast(bf16x8, *(const u16x8*)(Bs + row * 32 + g * 8));
    }
#pragma unroll
    for (int m = 0; m < 4; ++m)
#pragma unroll
      for (int n = 0; n < 4; ++n)
        acc[m][n] = mfma16(av[m], bv[n], acc[m][n]);
    __syncthreads();  // all reads done before next stage overwrites
  }

  // epilogue: C frag layout: row = fg*4 + reg, col = fr
#pragma unroll
  for (int m = 0; m < 4; ++m) {
#pragma unroll
    for (int n = 0; n < 4; ++n) {
      const int gcol = tileN + wc + n * 16 + fr;
      const int growb = tileM + wr + m * 16 + fg * 4;
#pragma unroll
      for (int r = 0; r < 4; ++r) {
        const int grow = growb + r;
        float v = acc[m][n][r];
        if constexpr (EPI == EPI_GATES) {
          ((u16*)Cp)[(size_t)grow * ldc + gcol] = f2b(v);
        } else if constexpr (EPI == EPI_H1) {
          v += bias[(grow >> 7) * 256 + gcol];   // p1[b][col]
          v = fmaxf(v, 0.f);
          ((u16*)Cp)[(size_t)grow * ldc + gcol] = f2b(v);
        } else if constexpr (EPI == EPI_H2) {
          v += bias[gcol];
          v = fmaxf(v, 0.f);
          ((u16*)Cp)[(size_t)grow * ldc + gcol] = f2b(v);
        } else {
          v += bias[gcol];
          ((float*)Cp)[(size_t)grow * ldc + gcol] = sigf(v);
        }
      }
    }
  }
}

// ---------------- fused LSTM scan + encoder + VQ + p1 ----------------
// one block (448 thr) per batch; thread r<400 owns gate rows {r, r+400} as
// 200 half2 (row-pair per k) in VGPRs; h splat via v_pk_fma_f16 op_sel.
__global__ __launch_bounds__(448, 1) void lstm_enc(
    const u16* __restrict__ gates, const unsigned* __restrict__ Wt2,
    const float* __restrict__ biasc,
    const float* __restrict__ Wenc, const float* __restrict__ b_enc,
    const float* __restrict__ emb, const float* __restrict__ W1,
    const float* __restrict__ b1, const float* __restrict__ noise,
    float* __restrict__ p1) {
  __shared__ __attribute__((aligned(16))) __half sh_h[208];
  __shared__ __attribute__((aligned(16))) float sh_hf[HID];
  __shared__ float sh_g[G4H];
  __shared__ __attribute__((aligned(16))) float sh_ze[LATENT];
  __shared__ float sh_zq[LATENT];
  __shared__ float sh_rd[448];
  __shared__ int sh_ri[448];
  const int r = threadIdx.x;
  const int b = blockIdx.x;
  const bool active = (r < 400);

  unsigned wv[200];
  float biasA = 0.f, biasB = 0.f;
  if (active) {
#pragma unroll
    for (int k = 0; k < 200; ++k) wv[k] = Wt2[(size_t)k * 400 + r];
    biasA = biasc[r];
    biasB = biasc[r + 400];
  }
  if (r < HID) sh_h[r] = __float2half(0.f);
  float c = 0.f;
  float gvA = 0.f, gvB = 0.f;
  if (active) {
    gvA = b2f(gates[(size_t)(b * TLEN) * LDG + r]);
    gvB = b2f(gates[(size_t)(b * TLEN) * LDG + r + 400]);
  }
  __syncthreads();

  for (int t = 0; t < TLEN; ++t) {
    float gvA_n = 0.f, gvB_n = 0.f;
    if (active && t + 1 < TLEN) {
      gvA_n = b2f(gates[(size_t)(b * TLEN + t + 1) * LDG + r]);
      gvB_n = b2f(gates[(size_t)(b * TLEN + t + 1) * LDG + r + 400]);
    }

    if (active) {
      unsigned a0 = 0, a1 = 0, a2 = 0, a3 = 0;
      const uint4* H = (const uint4*)sh_h;
#pragma unroll
      for (int q4 = 0; q4 < 25; ++q4) {
        uint4 hv = H[q4];  // h[8q4 .. 8q4+7] as 4 packed half-pairs
        // acc.lo += W[rA][k]*h[k]; acc.hi += W[rB][k]*h[k]  (h splat via op_sel)
        asm("v_pk_fma_f16 %0, %1, %2, %0 op_sel:[0,0,0] op_sel_hi:[1,0,1]"
            : "+v"(a0) : "v"(wv[8 * q4 + 0]), "v"(hv.x));
        asm("v_pk_fma_f16 %0, %1, %2, %0 op_sel:[0,1,0] op_sel_hi:[1,1,1]"
            : "+v"(a1) : "v"(wv[8 * q4 + 1]), "v"(hv.x));
        asm("v_pk_fma_f16 %0, %1, %2, %0 op_sel:[0,0,0] op_sel_hi:[1,0,1]"
            : "+v"(a2) : "v"(wv[8 * q4 + 2]), "v"(hv.y));
        asm("v_pk_fma_f16 %0, %1, %2, %0 op_sel:[0,1,0] op_sel_hi:[1,1,1]"
            : "+v"(a3) : "v"(wv[8 * q4 + 3]), "v"(hv.y));
        asm("v_pk_fma_f16 %0, %1, %2, %0 op_sel:[0,0,0] op_sel_hi:[1,0,1]"
            : "+v"(a0) : "v"(wv[8 * q4 + 4]), "v"(hv.z));
        asm("v_pk_fma_f16 %0, %1, %2, %0 op_sel:[0,1,0] op_sel_hi:[1,1,1]"
            : "+v"(a1) : "v"(wv[8 * q4 + 5]), "v"(hv.z));
        asm("v_pk_fma_f16 %0, %1, %2, %0 op_sel:[0,0,0] op_sel_hi:[1,0,1]"
            : "+v"(a2) : "v"(wv[8 * q4 + 6]), "v"(hv.w));
        asm("v_pk_fma_f16 %0, %1, %2, %0 op_sel:[0,1,0] op_sel_hi:[1,1,1]"
            : "+v"(a3) : "v"(wv[8 * q4 + 7]), "v"(hv.w));
      }
      __half2 s = __hadd2(__hadd2(__builtin_bit_cast(__half2, a0), __builtin_bit_cast(__half2, a1)),
                          __hadd2(__builtin_bit_cast(__half2, a2), __builtin_bit_cast(__half2, a3)));
      sh_g[r] = biasA + gvA + __low2float(s);
      sh_g[r + 400] = biasB + gvB + __high2float(s);
    }
    __syncthreads();  // gates visible; all sh_h reads complete
    if (r < HID) {
      float gi = sh_g[r], gf = sh_g[HID + r], gg = sh_g[2 * HID + r], go = sh_g[3 * HID + r];
      c = sigf(gf) * c + sigf(gi) * tanh_fast(gg);
      float h = sigf(go) * tanh_fast(c);
      sh_h[r] = __float2half(h);
      sh_hf[r] = h;
    }
    __syncthreads();  // new h visible
    gvA = gvA_n; gvB = gvB_n;
  }

  // encoder: z_e = h @ Wenc^T + b_enc
  if (r < LATENT) {
    float z = b_enc[r];
#pragma unroll 4
    for (int k = 0; k < HID; ++k) z = fmaf(Wenc[(size_t)r * HID + k], sh_hf[k], z);
    sh_ze[r] = z;
  }
  __syncthreads();

  // VQ: argmin_k ||e_k||^2 - 2 z_e . e_k
  float best = INFINITY; int bi = 0;
  for (int k = r; k < NCODES; k += 448) {
    float d = 0.f;
#pragma unroll
    for (int q = 0; q < LATENT / 4; ++q) {
      float4 e = *(const float4*)&emb[(size_t)k * LATENT + q * 4];
      float4 z = *(const float4*)&sh_ze[q * 4];
      d += e.x * (e.x - 2.f * z.x) + e.y * (e.y - 2.f * z.y)
         + e.z * (e.z - 2.f * z.z) + e.w * (e.w - 2.f * z.w);
    }
    if (d < best) { best = d; bi = k; }
  }
  sh_rd[r] = best; sh_ri[r] = bi;
  __syncthreads();
  for (int s = 256; s > 0; s >>= 1) {
    if (r < s && r + s < 448) {
      float od = sh_rd[r + s]; int oi = sh_ri[r + s];
      if (od < sh_rd[r] || (od == sh_rd[r] && oi < sh_ri[r])) { sh_rd[r] = od; sh_ri[r] = oi; }
    }
    __syncthreads();
  }
  const int kmin = sh_ri[0];
  if (r < LATENT) sh_zq[r] = emb[(size_t)kmin * LATENT + r];
  __syncthreads();

  // p1[b][j] = b1 + W1[:,0:128].zq + W1[:,1664:2432].noise  (pad cols 200..255 = 0)
  if (r < 256) {
    float v = 0.f;
    if (r < HID) {
      v = b1[r];
      const float* wrow = W1 + (size_t)r * 2432;
#pragma unroll 4
      for (int d = 0; d < LATENT; ++d) v = fmaf(wrow[d], sh_zq[d], v);
      const float* nz = noise + (size_t)b * DIN;
#pragma unroll 4
      for (int d = 0; d < DIN; ++d) v = fmaf(wrow[1664 + d], nz[d], v);
    }
    p1[b * 256 + r] = v;
  }
}

// ---------------- host ----------------
extern "C" void kernel_launch(void* const* d_in, const int* in_sizes, int n_in,
                              void* d_out, int out_size, void* d_ws, size_t ws_size,
                              hipStream_t stream) {
  const float* x     = (const float*)d_in[0];
  const float* cond  = (const float*)d_in[1];
  const float* noise = (const float*)d_in[2];
  const float* W_ih  = (const float*)d_in[3];
  const float* W_hh  = (const float*)d_in[4];
  const float* b_ih  = (const float*)d_in[5];
  const float* b_hh  = (const float*)d_in[6];
  const float* W_enc = (const float*)d_in[7];
  const float* b_enc = (const float*)d_in[8];
  const float* emb   = (const float*)d_in[9];
  const float* W1    = (const float*)d_in[10];
  const float* b1    = (const float*)d_in[11];
  const float* W2    = (const float*)d_in[12];
  const float* b2    = (const float*)d_in[13];
  const float* W3    = (const float*)d_in[14];
  const float* b3    = (const float*)d_in[15];

  char* ws = (char*)d_ws;
  size_t off = 0;
  auto alloc = [&](size_t bytes) -> void* {
    void* p = ws + off; off += (bytes + 255) & ~(size_t)255; return p;
  };
  u16*      W_ihb = (u16*)alloc((size_t)896 * 768 * 2);
  u16*      W1cb  = (u16*)alloc((size_t)256 * 1536 * 2);
  u16*      W2b   = (u16*)alloc((size_t)512 * 256 * 2);
  u16*      W3b   = (u16*)alloc((size_t)768 * 512 * 2);
  float*    b2p   = (float*)alloc(512 * 4);
  unsigned* Wt2   = (unsigned*)alloc((size_t)200 * 400 * 4);
  float*    biasc = (float*)alloc(G4H * 4);
  u16*      gates = (u16*)alloc((size_t)MROWS * LDG * 2);
  float*    p1    = (float*)alloc(256 * 256 * 4);
  u16*      h1    = (u16*)alloc((size_t)MROWS * LDH1 * 2);
  u16*      h2    = (u16*)alloc((size_t)MROWS * LDH2 * 2);

  cvt_pad<<<dim3((896 * 768 + 255) / 256), 256, 0, stream>>>(W_ih, W_ihb, 800, 768, 768, 0, 896, 768);
  cvt_pad<<<dim3((256 * 1536 + 255) / 256), 256, 0, stream>>>(W1, W1cb, 200, 1536, 2432, 128, 256, 1536);
  cvt_pad<<<dim3((512 * 256 + 255) / 256), 256, 0, stream>>>(W2, W2b, 400, 200, 200, 0, 512, 256);
  cvt_pad<<<dim3((768 * 512 + 255) / 256), 256, 0, stream>>>(W3, W3b, 768, 400, 400, 0, 768, 512);
  pad_f32<<<dim3(2), 256, 0, stream>>>(b2, b2p, 400, 512);
  pack_whh<<<dim3((200 * 400 + 255) / 256), 256, 0, stream>>>(W_hh, (__half2*)Wt2, b_ih, b_hh, biasc);

  // gates = x @ W_ih^T  (bias added in lstm kernel), bf16 out, ld 896
  gemm_bf16<true, EPI_GATES><<<dim3(LDG / 128, MROWS / 128), 256, 0, stream>>>(
      x, W_ihb, gates, 768, LDG, nullptr);

  // LSTM scan + encoder + VQ + p1
  lstm_enc<<<dim3(NB), 448, 0, stream>>>(gates, Wt2, biasc, W_enc, b_enc,
                                         emb, W1, b1, noise, p1);

  // h1 = relu(cond @ W1c^T + p1[b])
  gemm_bf16<true, EPI_H1><<<dim3(LDH1 / 128, MROWS / 128), 256, 0, stream>>>(
      cond, W1cb, h1, DCOND, LDH1, p1);
  // h2 = relu(h1 @ W2^T + b2)
  gemm_bf16<false, EPI_H2><<<dim3(LDH2 / 128, MROWS / 128), 256, 0, stream>>>(
      h1, W2b, h2, LDH1, LDH2, b2p);
  // out = sigmoid(h2 @ W3^T + b3)
  gemm_bf16<false, EPI_OUT><<<dim3(NOUT / 128, MROWS / 128), 256, 0, stream>>>(
      h2, W3b, (float*)d_out, LDH2, NOUT, b3);
}

// Round 4
// 576.435 us; speedup vs baseline: 3.2170x; 1.0016x over previous
//
#include <hip/hip_runtime.h>
#include <hip/hip_fp16.h>
#include <math.h>

typedef unsigned short u16;
typedef u16 u16x8 __attribute__((ext_vector_type(8)));
typedef __bf16 bf16x8 __attribute__((ext_vector_type(8)));
typedef float f32x4 __attribute__((ext_vector_type(4)));

#define HID 200
#define G4H 800
#define TLEN 128
#define LATENT 128
#define NCODES 1024
#define DIN 768
#define DCOND 1536
#define NB 256
#define MROWS (NB * TLEN)
#define LDG 896
#define LDH1 256
#define LDH2 512
#define NOUT 768

__device__ __forceinline__ u16 f2b(float f) {
  union { float f; unsigned u; } v; v.f = f;
  unsigned r = v.u + 0x7fffu + ((v.u >> 16) & 1u);
  return (u16)(r >> 16);
}
__device__ __forceinline__ float b2f(u16 h) {
  union { unsigned u; float f; } v; v.u = ((unsigned)h) << 16;
  return v.f;
}
__device__ __forceinline__ float sigf(float x) { return 1.f / (1.f + __expf(-x)); }
__device__ __forceinline__ float tanh_fast(float x) {
  return 1.f - 2.f / (__expf(2.f * x) + 1.f);
}

// async global->LDS, 16B per lane; LDS dest is wave-uniform base + lane*16
__device__ __forceinline__ void gl16(const void* g, void* l) {
  __builtin_amdgcn_global_load_lds(
      (const __attribute__((address_space(1))) void*)g,
      (__attribute__((address_space(3))) void*)l, 16, 0, 0);
}

// pack 2 f32 -> u32 of 2 bf16 (lo = first arg)
__device__ __forceinline__ unsigned cvtpk(float a, float b) {
  unsigned r;
  asm("v_cvt_pk_bf16_f32 %0, %1, %2" : "=v"(r) : "v"(a), "v"(b));
  return r;
}

// ---------------- weight convert + pad ----------------
__global__ void cvt_pad(const float* __restrict__ src, u16* __restrict__ dst,
                        int nr, int nc, int lds, int col0, int NRp, int KP) {
  int i = blockIdx.x * blockDim.x + threadIdx.x;
  if (i >= NRp * KP) return;
  int r = i / KP, c = i - r * KP;
  float v = (r < nr && c < nc) ? src[(size_t)r * lds + col0 + c] : 0.f;
  dst[i] = f2b(v);
}

__global__ void pad_f32(const float* __restrict__ src, float* __restrict__ dst,
                        int n, int npad) {
  int i = blockIdx.x * blockDim.x + threadIdx.x;
  if (i < npad) dst[i] = (i < n) ? src[i] : 0.f;
}

// W_hh [800][200] f32 -> Wt2[k][r] = half2(W[r][k], W[r+400][k]), k=0..199, r=0..399
__global__ void pack_whh(const float* __restrict__ Whh, __half2* __restrict__ Wt2,
                         const float* __restrict__ b_ih, const float* __restrict__ b_hh,
                         float* __restrict__ biasc) {
  int i = blockIdx.x * blockDim.x + threadIdx.x;
  if (i < 200 * 400) {
    int k = i / 400, r = i - k * 400;
    Wt2[i] = __floats2half2_rn(Whh[(size_t)r * HID + k], Whh[(size_t)(r + 400) * HID + k]);
  }
  if (i < G4H) biasc[i] = b_ih[i] + b_hh[i];
}

// ---------------- bf16 MFMA GEMM: C[M,N] = A[M,K] * B[N,K]^T (+epilogue) ----------------
enum { EPI_GATES = 0, EPI_H1 = 1, EPI_H2 = 2, EPI_OUT = 3 };

__device__ __forceinline__ f32x4 mfma16(bf16x8 a, bf16x8 b, f32x4 c) {
  return __builtin_amdgcn_mfma_f32_16x16x32_bf16(a, b, c, 0, 0, 0);
}

template<bool AF32, int EPI>
__global__ __launch_bounds__(256) void gemm_bf16(
    const void* __restrict__ Ap, const u16* __restrict__ Bp,
    void* __restrict__ Cp, int K, int ldc, const float* __restrict__ bias) {
  __shared__ __attribute__((aligned(16))) char AsRaw[AF32 ? 128 * 32 * 4 : 128 * 32 * 2];
  __shared__ __attribute__((aligned(16))) u16 Bs[128 * 32];
  float* Asf = (float*)AsRaw;
  u16* As16 = (u16*)AsRaw;

  const int t = threadIdx.x;
  const int tileN = blockIdx.x * 128;
  const int tileM = blockIdx.y * 128;
  const int l = t & 63;
  const int w = t >> 6;
  const int wr = (w >> 1) * 64;
  const int wc = (w & 1) * 64;
  const int fr = l & 15;
  const int fg = l >> 4;

  const u16* bsrc[2];
  u16* bdst[2];
#pragma unroll
  for (int j = 0; j < 2; ++j) {
    int tb = w * 1024 + j * 4096 + (t & 63) * 16;
    int row = tb >> 6, gd = (tb >> 4) & 3;
    bsrc[j] = Bp + (size_t)(tileN + row) * K + ((gd ^ ((row >> 1) & 3)) << 3);
    bdst[j] = Bs + w * 512 + j * 2048;
  }
  const float* asrcF[4];
  float* adstF[4];
  const u16* asrcH[2];
  u16* adstH[2];
  if constexpr (AF32) {
#pragma unroll
    for (int j = 0; j < 4; ++j) {
      int tb = w * 1024 + j * 4096 + (t & 63) * 16;
      int row = tb >> 7, gd = (tb >> 4) & 7;
      asrcF[j] = (const float*)Ap + (size_t)(tileM + row) * K + ((gd ^ (row & 7)) << 2);
      adstF[j] = Asf + w * 256 + j * 1024;
    }
  } else {
#pragma unroll
    for (int j = 0; j < 2; ++j) {
      int tb = w * 1024 + j * 4096 + (t & 63) * 16;
      int row = tb >> 6, gd = (tb >> 4) & 3;
      asrcH[j] = (const u16*)Ap + (size_t)(tileM + row) * K + ((gd ^ ((row >> 1) & 3)) << 3);
      adstH[j] = As16 + w * 512 + j * 2048;
    }
  }

  f32x4 acc[4][4];
#pragma unroll
  for (int m = 0; m < 4; ++m)
#pragma unroll
    for (int n = 0; n < 4; ++n) {
      f32x4 z = {0.f, 0.f, 0.f, 0.f};
      acc[m][n] = z;
    }

  for (int k0 = 0; k0 < K; k0 += 32) {
#pragma unroll
    for (int j = 0; j < 2; ++j) { gl16(bsrc[j], bdst[j]); bsrc[j] += 32; }
    if constexpr (AF32) {
#pragma unroll
      for (int j = 0; j < 4; ++j) { gl16(asrcF[j], adstF[j]); asrcF[j] += 32; }
    } else {
#pragma unroll
      for (int j = 0; j < 2; ++j) { gl16(asrcH[j], adstH[j]); asrcH[j] += 32; }
    }
    __syncthreads();

    bf16x8 av[4], bv[4];
#pragma unroll
    for (int m = 0; m < 4; ++m) {
      const int row = wr + m * 16 + fr;
      if constexpr (AF32) {
        const int g0 = (2 * fg) ^ (row & 7);
        const int g1 = (2 * fg + 1) ^ (row & 7);
        float4 p0 = *(const float4*)(Asf + row * 32 + g0 * 4);
        float4 p1 = *(const float4*)(Asf + row * 32 + g1 * 4);
        uint4 u;
        u.x = cvtpk(p0.x, p0.y); u.y = cvtpk(p0.z, p0.w);
        u.z = cvtpk(p1.x, p1.y); u.w = cvtpk(p1.z, p1.w);
        av[m] = __builtin_bit_cast(bf16x8, u);
      } else {
        const int g = fg ^ ((row >> 1) & 3);
        av[m] = __builtin_bit_cast(bf16x8, *(const u16x8*)(As16 + row * 32 + g * 8));
      }
    }
#pragma unroll
    for (int n = 0; n < 4; ++n) {
      const int row = wc + n * 16 + fr;
      const int g = fg ^ ((row >> 1) & 3);
      bv[n] = __builtin_bit_cast(bf16x8, *(const u16x8*)(Bs + row * 32 + g * 8));
    }
#pragma unroll
    for (int m = 0; m < 4; ++m)
#pragma unroll
      for (int n = 0; n < 4; ++n)
        acc[m][n] = mfma16(av[m], bv[n], acc[m][n]);
    __syncthreads();
  }

#pragma unroll
  for (int m = 0; m < 4; ++m) {
#pragma unroll
    for (int n = 0; n < 4; ++n) {
      const int gcol = tileN + wc + n * 16 + fr;
      const int growb = tileM + wr + m * 16 + fg * 4;
#pragma unroll
      for (int r = 0; r < 4; ++r) {
        const int grow = growb + r;
        float v = acc[m][n][r];
        if constexpr (EPI == EPI_GATES) {
          ((u16*)Cp)[(size_t)grow * ldc + gcol] = f2b(v);
        } else if constexpr (EPI == EPI_H1) {
          v += bias[(grow >> 7) * 256 + gcol];
          v = fmaxf(v, 0.f);
          ((u16*)Cp)[(size_t)grow * ldc + gcol] = f2b(v);
        } else if constexpr (EPI == EPI_H2) {
          v += bias[gcol];
          v = fmaxf(v, 0.f);
          ((u16*)Cp)[(size_t)grow * ldc + gcol] = f2b(v);
        } else {
          v += bias[gcol];
          ((float*)Cp)[(size_t)grow * ldc + gcol] = sigf(v);
        }
      }
    }
  }
}

// ---------------- fused LSTM scan + encoder + VQ + p1 ----------------
// one block (448 thr = 7 waves) per batch; thread r<400 owns gate rows {r, r+400}
// as 200 half2 in VGPRs. amdgpu_waves_per_eu(2,2) pins the occupancy target at
// 2 waves/SIMD -> firm 256-VGPR budget -> no spill (R3 spilled at 128).
__global__ __attribute__((amdgpu_flat_work_group_size(448, 448), amdgpu_waves_per_eu(2, 2)))
void lstm_enc(
    const u16* __restrict__ gates, const unsigned* __restrict__ Wt2,
    const float* __restrict__ biasc,
    const float* __restrict__ Wenc, const float* __restrict__ b_enc,
    const float* __restrict__ emb, const float* __restrict__ W1,
    const float* __restrict__ b1, const float* __restrict__ noise,
    float* __restrict__ p1) {
  __shared__ __attribute__((aligned(16))) __half sh_h[208];
  __shared__ __attribute__((aligned(16))) float sh_hf[HID];
  __shared__ float sh_g[G4H];
  __shared__ __attribute__((aligned(16))) float sh_ze[LATENT];
  __shared__ float sh_zq[LATENT];
  __shared__ float sh_rd[448];
  __shared__ int sh_ri[448];
  const int r = threadIdx.x;
  const int b = blockIdx.x;
  const bool active = (r < 400);

  unsigned wv[200];
  float biasA = 0.f, biasB = 0.f;
  if (active) {
#pragma unroll
    for (int k = 0; k < 200; ++k) wv[k] = Wt2[(size_t)k * 400 + r];
    biasA = biasc[r];
    biasB = biasc[r + 400];
  }
  if (r < HID) sh_h[r] = __float2half(0.f);
  float c = 0.f;
  float gvA = 0.f, gvB = 0.f;
  if (active) {
    gvA = b2f(gates[(size_t)(b * TLEN) * LDG + r]);
    gvB = b2f(gates[(size_t)(b * TLEN) * LDG + r + 400]);
  }
  __syncthreads();

  for (int t = 0; t < TLEN; ++t) {
    float gvA_n = 0.f, gvB_n = 0.f;
    if (active && t + 1 < TLEN) {
      gvA_n = b2f(gates[(size_t)(b * TLEN + t + 1) * LDG + r]);
      gvB_n = b2f(gates[(size_t)(b * TLEN + t + 1) * LDG + r + 400]);
    }

    if (active) {
      unsigned a0 = 0, a1 = 0, a2 = 0, a3 = 0;
      const uint4* H = (const uint4*)sh_h;
#pragma unroll
      for (int q4 = 0; q4 < 25; ++q4) {
        uint4 hv = H[q4];  // h[8q4 .. 8q4+7] as 4 packed half-pairs
        asm("v_pk_fma_f16 %0, %1, %2, %0 op_sel:[0,0,0] op_sel_hi:[1,0,1]"
            : "+v"(a0) : "v"(wv[8 * q4 + 0]), "v"(hv.x));
        asm("v_pk_fma_f16 %0, %1, %2, %0 op_sel:[0,1,0] op_sel_hi:[1,1,1]"
            : "+v"(a1) : "v"(wv[8 * q4 + 1]), "v"(hv.x));
        asm("v_pk_fma_f16 %0, %1, %2, %0 op_sel:[0,0,0] op_sel_hi:[1,0,1]"
            : "+v"(a2) : "v"(wv[8 * q4 + 2]), "v"(hv.y));
        asm("v_pk_fma_f16 %0, %1, %2, %0 op_sel:[0,1,0] op_sel_hi:[1,1,1]"
            : "+v"(a3) : "v"(wv[8 * q4 + 3]), "v"(hv.y));
        asm("v_pk_fma_f16 %0, %1, %2, %0 op_sel:[0,0,0] op_sel_hi:[1,0,1]"
            : "+v"(a0) : "v"(wv[8 * q4 + 4]), "v"(hv.z));
        asm("v_pk_fma_f16 %0, %1, %2, %0 op_sel:[0,1,0] op_sel_hi:[1,1,1]"
            : "+v"(a1) : "v"(wv[8 * q4 + 5]), "v"(hv.z));
        asm("v_pk_fma_f16 %0, %1, %2, %0 op_sel:[0,0,0] op_sel_hi:[1,0,1]"
            : "+v"(a2) : "v"(wv[8 * q4 + 6]), "v"(hv.w));
        asm("v_pk_fma_f16 %0, %1, %2, %0 op_sel:[0,1,0] op_sel_hi:[1,1,1]"
            : "+v"(a3) : "v"(wv[8 * q4 + 7]), "v"(hv.w));
      }
      __half2 s = __hadd2(__hadd2(__builtin_bit_cast(__half2, a0), __builtin_bit_cast(__half2, a1)),
                          __hadd2(__builtin_bit_cast(__half2, a2), __builtin_bit_cast(__half2, a3)));
      sh_g[r] = biasA + gvA + __low2float(s);
      sh_g[r + 400] = biasB + gvB + __high2float(s);
    }
    __syncthreads();
    if (r < HID) {
      float gi = sh_g[r], gf = sh_g[HID + r], gg = sh_g[2 * HID + r], go = sh_g[3 * HID + r];
      c = sigf(gf) * c + sigf(gi) * tanh_fast(gg);
      float h = sigf(go) * tanh_fast(c);
      sh_h[r] = __float2half(h);
      sh_hf[r] = h;
    }
    __syncthreads();
    gvA = gvA_n; gvB = gvB_n;
  }

  // encoder: z_e = h @ Wenc^T + b_enc
  if (r < LATENT) {
    float z = b_enc[r];
#pragma unroll 4
    for (int k = 0; k < HID; ++k) z = fmaf(Wenc[(size_t)r * HID + k], sh_hf[k], z);
    sh_ze[r] = z;
  }
  __syncthreads();

  // VQ: argmin_k ||e_k||^2 - 2 z_e . e_k
  float best = INFINITY; int bi = 0;
  for (int k = r; k < NCODES; k += 448) {
    float d = 0.f;
#pragma unroll
    for (int q = 0; q < LATENT / 4; ++q) {
      float4 e = *(const float4*)&emb[(size_t)k * LATENT + q * 4];
      float4 z = *(const float4*)&sh_ze[q * 4];
      d += e.x * (e.x - 2.f * z.x) + e.y * (e.y - 2.f * z.y)
         + e.z * (e.z - 2.f * z.z) + e.w * (e.w - 2.f * z.w);
    }
    if (d < best) { best = d; bi = k; }
  }
  sh_rd[r] = best; sh_ri[r] = bi;
  __syncthreads();
  for (int s = 256; s > 0; s >>= 1) {
    if (r < s && r + s < 448) {
      float od = sh_rd[r + s]; int oi = sh_ri[r + s];
      if (od < sh_rd[r] || (od == sh_rd[r] && oi < sh_ri[r])) { sh_rd[r] = od; sh_ri[r] = oi; }
    }
    __syncthreads();
  }
  const int kmin = sh_ri[0];
  if (r < LATENT) sh_zq[r] = emb[(size_t)kmin * LATENT + r];
  __syncthreads();

  // p1[b][j] = b1 + W1[:,0:128].zq + W1[:,1664:2432].noise  (pad cols 200..255 = 0)
  if (r < 256) {
    float v = 0.f;
    if (r < HID) {
      v = b1[r];
      const float* wrow = W1 + (size_t)r * 2432;
#pragma unroll 4
      for (int d = 0; d < LATENT; ++d) v = fmaf(wrow[d], sh_zq[d], v);
      const float* nz = noise + (size_t)b * DIN;
#pragma unroll 4
      for (int d = 0; d < DIN; ++d) v = fmaf(wrow[1664 + d], nz[d], v);
    }
    p1[b * 256 + r] = v;
  }
}

// ---------------- host ----------------
extern "C" void kernel_launch(void* const* d_in, const int* in_sizes, int n_in,
                              void* d_out, int out_size, void* d_ws, size_t ws_size,
                              hipStream_t stream) {
  const float* x     = (const float*)d_in[0];
  const float* cond  = (const float*)d_in[1];
  const float* noise = (const float*)d_in[2];
  const float* W_ih  = (const float*)d_in[3];
  const float* W_hh  = (const float*)d_in[4];
  const float* b_ih  = (const float*)d_in[5];
  const float* b_hh  = (const float*)d_in[6];
  const float* W_enc = (const float*)d_in[7];
  const float* b_enc = (const float*)d_in[8];
  const float* emb   = (const float*)d_in[9];
  const float* W1    = (const float*)d_in[10];
  const float* b1    = (const float*)d_in[11];
  const float* W2    = (const float*)d_in[12];
  const float* b2    = (const float*)d_in[13];
  const float* W3    = (const float*)d_in[14];
  const float* b3    = (const float*)d_in[15];

  char* ws = (char*)d_ws;
  size_t off = 0;
  auto alloc = [&](size_t bytes) -> void* {
    void* p = ws + off; off += (bytes + 255) & ~(size_t)255; return p;
  };
  u16*      W_ihb = (u16*)alloc((size_t)896 * 768 * 2);
  u16*      W1cb  = (u16*)alloc((size_t)256 * 1536 * 2);
  u16*      W2b   = (u16*)alloc((size_t)512 * 256 * 2);
  u16*      W3b   = (u16*)alloc((size_t)768 * 512 * 2);
  float*    b2p   = (float*)alloc(512 * 4);
  unsigned* Wt2   = (unsigned*)alloc((size_t)200 * 400 * 4);
  float*    biasc = (float*)alloc(G4H * 4);
  u16*      gates = (u16*)alloc((size_t)MROWS * LDG * 2);
  float*    p1    = (float*)alloc(256 * 256 * 4);
  u16*      h1    = (u16*)alloc((size_t)MROWS * LDH1 * 2);
  u16*      h2    = (u16*)alloc((size_t)MROWS * LDH2 * 2);

  cvt_pad<<<dim3((896 * 768 + 255) / 256), 256, 0, stream>>>(W_ih, W_ihb, 800, 768, 768, 0, 896, 768);
  cvt_pad<<<dim3((256 * 1536 + 255) / 256), 256, 0, stream>>>(W1, W1cb, 200, 1536, 2432, 128, 256, 1536);
  cvt_pad<<<dim3((512 * 256 + 255) / 256), 256, 0, stream>>>(W2, W2b, 400, 200, 200, 0, 512, 256);
  cvt_pad<<<dim3((768 * 512 + 255) / 256), 256, 0, stream>>>(W3, W3b, 768, 400, 400, 0, 768, 512);
  pad_f32<<<dim3(2), 256, 0, stream>>>(b2, b2p, 400, 512);
  pack_whh<<<dim3((200 * 400 + 255) / 256), 256, 0, stream>>>(W_hh, (__half2*)Wt2, b_ih, b_hh, biasc);

  // gates = x @ W_ih^T  (bias added in lstm kernel), bf16 out, ld 896
  gemm_bf16<true, EPI_GATES><<<dim3(LDG / 128, MROWS / 128), 256, 0, stream>>>(
      x, W_ihb, gates, 768, LDG, nullptr);

  // LSTM scan + encoder + VQ + p1
  lstm_enc<<<dim3(NB), 448, 0, stream>>>(gates, Wt2, biasc, W_enc, b_enc,
                                         emb, W1, b1, noise, p1);

  // h1 = relu(cond @ W1c^T + p1[b])
  gemm_bf16<true, EPI_H1><<<dim3(LDH1 / 128, MROWS / 128), 256, 0, stream>>>(
      cond, W1cb, h1, DCOND, LDH1, p1);
  // h2 = relu(h1 @ W2^T + b2)
  gemm_bf16<false, EPI_H2><<<dim3(LDH2 / 128, MROWS / 128), 256, 0, stream>>>(
      h1, W2b, h2, LDH1, LDH2, b2p);
  // out = sigmoid(h2 @ W3^T + b3)
  gemm_bf16<false, EPI_OUT><<<dim3(NOUT / 128, MROWS / 128), 256, 0, stream>>>(
      h2, W3b, (float*)d_out, LDH2, NOUT, b3);
}